// Round 1
// baseline (1423.358 us; speedup 1.0000x reference)
//
#include <hip/hip_runtime.h>
#include <cstddef>

#define B_ 4
#define L_ 1024
#define H_ 16
#define DH_ 64
#define HID_ 1024

// ---------------------------------------------------------------------------
// Tiled fp32 GEMM: C = A[M,K] @ W[K,N] + bias[N]
// heads_layout=1: write C[m= b*L+l][n= h*64+d] -> out[((b*16+h)*1024+l)*64+d]
// BM=BN=64, BK=16, 256 threads, 4x4 micro-tile per thread.
// ---------------------------------------------------------------------------
__global__ __launch_bounds__(256) void gemm_bias_k(
    const float* __restrict__ A, const float* __restrict__ W,
    const float* __restrict__ bias, float* __restrict__ C,
    int M, int N, int K, int heads_layout)
{
    __shared__ float As[16][68];   // [kk][i], stride 68 floats = 272B (16B mult)
    __shared__ float Ws[16][68];   // [kk][j]

    const int t  = threadIdx.x;
    const int tx = t & 15;         // col group
    const int ty = t >> 4;         // row group
    const int m0 = blockIdx.y << 6;
    const int n0 = blockIdx.x << 6;

    float acc[4][4] = {};

    for (int k0 = 0; k0 < K; k0 += 16) {
        {   // A tile: 64 rows x 16 k
            const int i  = t >> 2;
            const int kk = (t & 3) << 2;
            float4 av = *(const float4*)&A[(size_t)(m0 + i) * K + k0 + kk];
            As[kk + 0][i] = av.x;
            As[kk + 1][i] = av.y;
            As[kk + 2][i] = av.z;
            As[kk + 3][i] = av.w;
        }
        {   // W tile: 16 k x 64 n
            const int kk = t >> 4;
            const int j  = (t & 15) << 2;
            *(float4*)&Ws[kk][j] = *(const float4*)&W[(size_t)(k0 + kk) * N + n0 + j];
        }
        __syncthreads();
#pragma unroll
        for (int kk = 0; kk < 16; ++kk) {
            float4 a = *(const float4*)&As[kk][ty << 2];
            float4 w = *(const float4*)&Ws[kk][tx << 2];
            float av[4] = {a.x, a.y, a.z, a.w};
            float wv[4] = {w.x, w.y, w.z, w.w};
#pragma unroll
            for (int ii = 0; ii < 4; ++ii)
#pragma unroll
                for (int jj = 0; jj < 4; ++jj)
                    acc[ii][jj] = fmaf(av[ii], wv[jj], acc[ii][jj]);
        }
        __syncthreads();
    }

    const int n = n0 + (tx << 2);
    float4 bv = *(const float4*)&bias[n];
#pragma unroll
    for (int ii = 0; ii < 4; ++ii) {
        const int m = m0 + (ty << 2) + ii;
        float4 cv;
        cv.x = acc[ii][0] + bv.x;
        cv.y = acc[ii][1] + bv.y;
        cv.z = acc[ii][2] + bv.z;
        cv.w = acc[ii][3] + bv.w;
        if (heads_layout) {
            const int b = m >> 10, l = m & 1023;
            const int h = n >> 6,  d = n & 63;
            *(float4*)&C[(((size_t)(b * H_ + h) << 10) + l) * DH_ + d] = cv;
        } else {
            *(float4*)&C[(size_t)m * N + n] = cv;
        }
    }
}

// ---------------------------------------------------------------------------
// Attention per (b, h, 64-row Q tile). Flash-style over 64-col K/V tiles.
// scores[i][j] = clip(q_i.k_j / 8) + q_i . rel_emb[i-j+1023]
// e = exp(scores) (no max-subtract: |scores| is O(1) with 0.02-scaled weights)
// ctx_i = sum_j e*v_j / sum_j e   ->  ctx layout [B][L][H][DH]
// ---------------------------------------------------------------------------
__global__ __launch_bounds__(256) void attn_k(
    const float* __restrict__ q, const float* __restrict__ k,
    const float* __restrict__ v, const float* __restrict__ rel,
    float* __restrict__ ctx)
{
    __shared__ float Qs[64][68];   // [i][d]
    __shared__ float Ks[64][68];   // [jj][d]
    __shared__ float Vs[64][68];   // [jj][d]
    __shared__ float Rs[127][65];  // band rows of rel_emb, stride 65 (odd: banks spread)
    __shared__ float Es[64][65];   // exp(scores) tile

    const int t  = threadIdx.x;
    const int i0 = blockIdx.x << 6;
    const int h  = blockIdx.y;
    const int b  = blockIdx.z;
    const size_t base = (size_t)(b * H_ + h) << 16;   // * L * DH

    const int wi = t >> 4;        // 0..15 -> rows ib..ib+3
    const int wj = t & 15;        // 0..15 -> S-cols jb..jb+3 / PV d-cols jb..jb+3
    const int ib = wi << 2;
    const int jb = wj << 2;

    {   // load Q tile (once)
        const int r = t >> 2, c = (t & 3) << 4;
#pragma unroll
        for (int u = 0; u < 4; ++u)
            *(float4*)&Qs[r][c + (u << 2)] =
                *(const float4*)&q[base + ((size_t)(i0 + r) << 6) + c + (u << 2)];
    }

    float acc[4][4] = {};   // ctx numerator: rows ib+a, d cols jb..jb+3
    float den[4]    = {};   // partial softmax denominators for rows ib+a

    for (int j0 = 0; j0 < L_; j0 += 64) {
        __syncthreads();   // previous iteration's readers done
        {   // load K,V tiles
            const int r = t >> 2, c = (t & 3) << 4;
#pragma unroll
            for (int u = 0; u < 4; ++u) {
                *(float4*)&Ks[r][c + (u << 2)] =
                    *(const float4*)&k[base + ((size_t)(j0 + r) << 6) + c + (u << 2)];
                *(float4*)&Vs[r][c + (u << 2)] =
                    *(const float4*)&v[base + ((size_t)(j0 + r) << 6) + c + (u << 2)];
            }
        }
        // rel band: rows rbase..rbase+126  (always within [0, 2046])
        const int rbase = i0 - j0 + 960;
        for (int idx = t; idx < 127 * 64; idx += 256) {
            const int rr = idx >> 6, dd = idx & 63;
            Rs[rr][dd] = rel[((size_t)(rbase + rr) << 6) + dd];
        }
        __syncthreads();

        // S tile, 4x4 per thread; rel rows needed: (ib+a)-(jb+bb)+63 = r0 + (a-bb+3)
        float sqk[4][4] = {}, srl[4][4] = {};
        const int r0 = ib - jb + 60;
#pragma unroll 2
        for (int d4 = 0; d4 < 16; ++d4) {
            const int dc = d4 << 2;
            float qv[4][4], kv[4][4], rv[7][4];
#pragma unroll
            for (int a = 0; a < 4; ++a) {
                float4 f = *(const float4*)&Qs[ib + a][dc];
                qv[a][0] = f.x; qv[a][1] = f.y; qv[a][2] = f.z; qv[a][3] = f.w;
            }
#pragma unroll
            for (int bb = 0; bb < 4; ++bb) {
                float4 f = *(const float4*)&Ks[jb + bb][dc];
                kv[bb][0] = f.x; kv[bb][1] = f.y; kv[bb][2] = f.z; kv[bb][3] = f.w;
            }
#pragma unroll
            for (int c = 0; c < 7; ++c)
#pragma unroll
                for (int u = 0; u < 4; ++u)
                    rv[c][u] = Rs[r0 + c][dc + u];
#pragma unroll
            for (int a = 0; a < 4; ++a)
#pragma unroll
                for (int bb = 0; bb < 4; ++bb)
#pragma unroll
                    for (int u = 0; u < 4; ++u) {
                        sqk[a][bb] = fmaf(qv[a][u], kv[bb][u], sqk[a][bb]);
                        srl[a][bb] = fmaf(qv[a][u], rv[a - bb + 3][u], srl[a][bb]);
                    }
        }
        // exp, stash tile, accumulate denominator
#pragma unroll
        for (int a = 0; a < 4; ++a)
#pragma unroll
            for (int bb = 0; bb < 4; ++bb) {
                float s = sqk[a][bb] * 0.125f;              // / sqrt(64)
                s = fminf(fmaxf(s, -100000.0f), 100000.0f); // clip (qk term only)
                float e = __expf(s + srl[a][bb]);
                Es[ib + a][jb + bb] = e;
                den[a] += e;
            }
        __syncthreads();

        // PV: rows ib+a, d columns jb..jb+3
#pragma unroll 4
        for (int jj = 0; jj < 64; ++jj) {
            float4 vv = *(const float4*)&Vs[jj][jb];
            float ev[4];
#pragma unroll
            for (int a = 0; a < 4; ++a) ev[a] = Es[ib + a][jj];
#pragma unroll
            for (int a = 0; a < 4; ++a) {
                acc[a][0] = fmaf(ev[a], vv.x, acc[a][0]);
                acc[a][1] = fmaf(ev[a], vv.y, acc[a][1]);
                acc[a][2] = fmaf(ev[a], vv.z, acc[a][2]);
                acc[a][3] = fmaf(ev[a], vv.w, acc[a][3]);
            }
        }
    }

    // reduce den over the 16 wj lanes (lanes wi*16..wi*16+15, intra-wave)
#pragma unroll
    for (int off = 1; off < 16; off <<= 1)
#pragma unroll
        for (int a = 0; a < 4; ++a)
            den[a] += __shfl_xor(den[a], off);

#pragma unroll
    for (int a = 0; a < 4; ++a) {
        const float inv = 1.0f / den[a];
        float4 o;
        o.x = acc[a][0] * inv; o.y = acc[a][1] * inv;
        o.z = acc[a][2] * inv; o.w = acc[a][3] * inv;
        const int l = i0 + ib + a;
        *(float4*)&ctx[(((size_t)(b * L_ + l)) * H_ + h) * DH_ + jb] = o;
    }
}

// ---------------------------------------------------------------------------
extern "C" void kernel_launch(void* const* d_in, const int* in_sizes, int n_in,
                              void* d_out, int out_size, void* d_ws, size_t ws_size,
                              hipStream_t stream)
{
    const float* x   = (const float*)d_in[0];
    const float* Wq  = (const float*)d_in[1];
    const float* bq  = (const float*)d_in[2];
    const float* Wk  = (const float*)d_in[3];
    const float* bk  = (const float*)d_in[4];
    const float* Wv  = (const float*)d_in[5];
    const float* bv  = (const float*)d_in[6];
    const float* Wo  = (const float*)d_in[7];
    const float* bo  = (const float*)d_in[8];
    const float* rel = (const float*)d_in[9];
    float* out = (float*)d_out;
    float* ws  = (float*)d_ws;

    const size_t HEADSZ = (size_t)B_ * H_ * L_ * DH_;  // 4,194,304 floats
    float* qw = ws;
    float* kw = ws + HEADSZ;
    float* vw = ws + 2 * HEADSZ;
    float* cw = ws + 3 * HEADSZ;   // ctx in [B][L][H][DH] = [4096][1024]

    dim3 gg(HID_ / 64, (B_ * L_) / 64);   // (16, 64)
    gemm_bias_k<<<gg, 256, 0, stream>>>(x,  Wq, bq, qw, B_ * L_, HID_, HID_, 1);
    gemm_bias_k<<<gg, 256, 0, stream>>>(x,  Wk, bk, kw, B_ * L_, HID_, HID_, 1);
    gemm_bias_k<<<gg, 256, 0, stream>>>(x,  Wv, bv, vw, B_ * L_, HID_, HID_, 1);

    attn_k<<<dim3(L_ / 64, H_, B_), 256, 0, stream>>>(qw, kw, vw, rel, cw);

    gemm_bias_k<<<gg, 256, 0, stream>>>(cw, Wo, bo, out, B_ * L_, HID_, HID_, 0);
}

// Round 3
// 1020.219 us; speedup vs baseline: 1.3951x; 1.3951x over previous
//
#include <hip/hip_runtime.h>
#include <cstddef>

#define B_ 4
#define L_ 1024
#define H_ 16
#define DH_ 64
#define HID_ 1024

typedef short bf16x8 __attribute__((ext_vector_type(8)));
typedef float f32x4  __attribute__((ext_vector_type(4)));

__device__ __forceinline__ short f2bf(float f) {
    unsigned u = __float_as_uint(f);
    u = (u + 0x7fffu + ((u >> 16) & 1u)) >> 16;   // RNE
    return (short)u;
}

// ---------------------------------------------------------------------------
// Transpose + cast: Wt[n][k] (bf16) = W[k][n] (f32).  64x64 tiles.
// ---------------------------------------------------------------------------
__global__ __launch_bounds__(256) void wcast_k(
    const float* __restrict__ W, short* __restrict__ Wt)
{
    __shared__ float T[64][65];
    const int t  = threadIdx.x;
    const int k0 = blockIdx.x << 6, n0 = blockIdx.y << 6;
    const int r  = t & 63;          // row within tile
    const int cg = t >> 6;          // 0..3 -> 16 cols
#pragma unroll
    for (int u = 0; u < 4; ++u) {
        float4 f = *(const float4*)&W[(size_t)(k0 + r) * HID_ + n0 + (cg << 4) + (u << 2)];
        T[r][(cg << 4) + (u << 2) + 0] = f.x;
        T[r][(cg << 4) + (u << 2) + 1] = f.y;
        T[r][(cg << 4) + (u << 2) + 2] = f.z;
        T[r][(cg << 4) + (u << 2) + 3] = f.w;
    }
    __syncthreads();
    bf16x8 p0, p1;
#pragma unroll
    for (int j = 0; j < 8; ++j) p0[j] = f2bf(T[(cg << 4) + j][r]);
#pragma unroll
    for (int j = 0; j < 8; ++j) p1[j] = f2bf(T[(cg << 4) + 8 + j][r]);
    short* dst = &Wt[(size_t)(n0 + r) * HID_ + k0 + (cg << 4)];
    *(bf16x8*)dst       = p0;
    *(bf16x8*)(dst + 8) = p1;
}

// ---------------------------------------------------------------------------
// bf16 MFMA GEMM: C = A(f32,[M,K]) @ Wt^T + bias  (Wt is [N,K] bf16).
// 128x128 tile, BK=32, 256 thr = 4 waves, each wave a 64x64 quadrant of C
// via 4x4 grid of 16x16x32 MFMAs. fp32 accumulate.
// mode 0: C[m][n] flat.  mode 1: heads layout [B,H,L,DH].
// ---------------------------------------------------------------------------
__global__ __launch_bounds__(256) void gemm_mfma_k(
    const float* __restrict__ A, const short* __restrict__ Wt,
    const float* __restrict__ bias, float* __restrict__ C,
    int M, int N, int K, int mode)
{
    __shared__ short As[128 * 40];   // [m][k] stride 40 (80B rows: 16B mult, 2-way free)
    __shared__ short Bs[128 * 40];   // [n][k] stride 40

    const int t    = threadIdx.x;
    const int m0   = blockIdx.y << 7, n0 = blockIdx.x << 7;
    const int lane = t & 63, wv = t >> 6;
    const int wm0  = (wv & 1) << 6, wn0 = (wv >> 1) << 6;
    const int fr   = lane & 15, quad = lane >> 4;

    const int sr = t >> 1;              // staging row 0..127
    const int kh = (t & 1) << 4;        // 0 / 16

    f32x4 acc[4][4];
#pragma unroll
    for (int i = 0; i < 4; ++i)
#pragma unroll
        for (int j = 0; j < 4; ++j) acc[i][j] = (f32x4){0.f, 0.f, 0.f, 0.f};

    const float* aptr = A  + (size_t)(m0 + sr) * K + kh;
    const short* bptr = Wt + (size_t)(n0 + sr) * K + kh;

    for (int k0 = 0; k0 < K; k0 += 32) {
        float4 a0 = *(const float4*)(aptr + k0);
        float4 a1 = *(const float4*)(aptr + k0 + 4);
        float4 a2 = *(const float4*)(aptr + k0 + 8);
        float4 a3 = *(const float4*)(aptr + k0 + 12);
        bf16x8 w0 = *(const bf16x8*)(bptr + k0);
        bf16x8 w1 = *(const bf16x8*)(bptr + k0 + 8);

        __syncthreads();   // previous iter's fragment reads complete
        bf16x8 p0, p1;
        p0[0] = f2bf(a0.x); p0[1] = f2bf(a0.y); p0[2] = f2bf(a0.z); p0[3] = f2bf(a0.w);
        p0[4] = f2bf(a1.x); p0[5] = f2bf(a1.y); p0[6] = f2bf(a1.z); p0[7] = f2bf(a1.w);
        p1[0] = f2bf(a2.x); p1[1] = f2bf(a2.y); p1[2] = f2bf(a2.z); p1[3] = f2bf(a2.w);
        p1[4] = f2bf(a3.x); p1[5] = f2bf(a3.y); p1[6] = f2bf(a3.z); p1[7] = f2bf(a3.w);
        *(bf16x8*)&As[sr * 40 + kh]     = p0;
        *(bf16x8*)&As[sr * 40 + kh + 8] = p1;
        *(bf16x8*)&Bs[sr * 40 + kh]     = w0;
        *(bf16x8*)&Bs[sr * 40 + kh + 8] = w1;
        __syncthreads();   // staging visible

        bf16x8 af[4], bf[4];
#pragma unroll
        for (int mt = 0; mt < 4; ++mt)
            af[mt] = *(const bf16x8*)&As[(wm0 + (mt << 4) + fr) * 40 + (quad << 3)];
#pragma unroll
        for (int nt = 0; nt < 4; ++nt)
            bf[nt] = *(const bf16x8*)&Bs[(wn0 + (nt << 4) + fr) * 40 + (quad << 3)];
#pragma unroll
        for (int mt = 0; mt < 4; ++mt)
#pragma unroll
            for (int nt = 0; nt < 4; ++nt)
                acc[mt][nt] = __builtin_amdgcn_mfma_f32_16x16x32_bf16(
                    af[mt], bf[nt], acc[mt][nt], 0, 0, 0);
    }

    float bv[4];
#pragma unroll
    for (int nt = 0; nt < 4; ++nt) bv[nt] = bias[n0 + wn0 + (nt << 4) + fr];

#pragma unroll
    for (int mt = 0; mt < 4; ++mt)
#pragma unroll
        for (int nt = 0; nt < 4; ++nt)
#pragma unroll
            for (int r = 0; r < 4; ++r) {
                const int row  = m0 + wm0 + (mt << 4) + (quad << 2) + r;
                const int coln = n0 + wn0 + (nt << 4) + fr;
                const float val = acc[mt][nt][r] + bv[nt];
                if (mode == 0) {
                    C[(size_t)row * N + coln] = val;
                } else {
                    const int b = row >> 10, l = row & 1023;
                    const int h = coln >> 6, d = coln & 63;
                    C[(((size_t)(b * H_ + h) << 10) + l) * DH_ + d] = val;
                }
            }
}

// ---------------------------------------------------------------------------
// Attention per (b, h, 64-row Q tile). Flash-style over 64-col K/V tiles.
// Ks 16B-group XOR swizzle: group of column c+4u is (c>>2)+u (R2 bug: had
// (c>>2)+(u<<2), collapsing 16 groups onto 7 slots). Read side: d4 ^ sk.
// ---------------------------------------------------------------------------
__global__ __launch_bounds__(256) void attn_k(
    const float* __restrict__ q, const float* __restrict__ k,
    const float* __restrict__ v, const float* __restrict__ rel,
    float* __restrict__ ctx)
{
    __shared__ float Qs[64][68];
    __shared__ float Ks[64][68];   // swizzled: group g stored at g ^ ((row>>3)&3)
    __shared__ float Vs[64][68];
    __shared__ float Rs[127][65];
    __shared__ float Es[64][65];

    const int t  = threadIdx.x;
    const int i0 = blockIdx.x << 6;
    const int h  = blockIdx.y;
    const int b  = blockIdx.z;
    const size_t base = (size_t)(b * H_ + h) << 16;

    const int wi = t >> 4;
    const int wj = t & 15;
    const int ib = wi << 2;
    const int jb = wj << 2;

    {   // load Q tile (once)
        const int r = t >> 2, c = (t & 3) << 4;
#pragma unroll
        for (int u = 0; u < 4; ++u)
            *(float4*)&Qs[r][c + (u << 2)] =
                *(const float4*)&q[base + ((size_t)(i0 + r) << 6) + c + (u << 2)];
    }

    float acc[4][4] = {};
    float den[4]    = {};

    for (int j0 = 0; j0 < L_; j0 += 64) {
        __syncthreads();
        {   // load K (swizzled), V tiles
            const int r = t >> 2, c = (t & 3) << 4;
            const int sk = (r >> 3) & 3;
#pragma unroll
            for (int u = 0; u < 4; ++u) {
                float4 kv = *(const float4*)&k[base + ((size_t)(j0 + r) << 6) + c + (u << 2)];
                float4 vv = *(const float4*)&v[base + ((size_t)(j0 + r) << 6) + c + (u << 2)];
                const int g = ((c >> 2) + u) ^ sk;    // FIXED: column group is c/4 + u
                *(float4*)&Ks[r][g << 2]      = kv;
                *(float4*)&Vs[r][c + (u << 2)] = vv;
            }
        }
        const int rbase = i0 - j0 + 960;
        for (int idx = t; idx < 127 * 64; idx += 256) {
            const int rr = idx >> 6, dd = idx & 63;
            Rs[rr][dd] = rel[((size_t)(rbase + rr) << 6) + dd];
        }
        __syncthreads();

        float sqk[4][4] = {}, srl[4][4] = {};
        const int r0 = ib - jb + 60;
#pragma unroll 2
        for (int d4 = 0; d4 < 16; ++d4) {
            const int dc = d4 << 2;
            float qv[4][4], kv[4][4], rv[7][4];
#pragma unroll
            for (int a = 0; a < 4; ++a) {
                float4 f = *(const float4*)&Qs[ib + a][dc];
                qv[a][0] = f.x; qv[a][1] = f.y; qv[a][2] = f.z; qv[a][3] = f.w;
            }
#pragma unroll
            for (int bb = 0; bb < 4; ++bb) {
                const int row = jb + bb;
                const int gg  = (d4 ^ ((row >> 3) & 3)) << 2;   // swizzled group
                float4 f = *(const float4*)&Ks[row][gg];
                kv[bb][0] = f.x; kv[bb][1] = f.y; kv[bb][2] = f.z; kv[bb][3] = f.w;
            }
#pragma unroll
            for (int c = 0; c < 7; ++c)
#pragma unroll
                for (int u = 0; u < 4; ++u)
                    rv[c][u] = Rs[r0 + c][dc + u];
#pragma unroll
            for (int a = 0; a < 4; ++a)
#pragma unroll
                for (int bb = 0; bb < 4; ++bb)
#pragma unroll
                    for (int u = 0; u < 4; ++u) {
                        sqk[a][bb] = fmaf(qv[a][u], kv[bb][u], sqk[a][bb]);
                        srl[a][bb] = fmaf(qv[a][u], rv[a - bb + 3][u], srl[a][bb]);
                    }
        }
#pragma unroll
        for (int a = 0; a < 4; ++a)
#pragma unroll
            for (int bb = 0; bb < 4; ++bb) {
                float s = sqk[a][bb] * 0.125f;
                s = fminf(fmaxf(s, -100000.0f), 100000.0f);
                float e = __expf(s + srl[a][bb]);
                Es[ib + a][jb + bb] = e;
                den[a] += e;
            }
        __syncthreads();

#pragma unroll 4
        for (int jj = 0; jj < 64; ++jj) {
            float4 vv = *(const float4*)&Vs[jj][jb];
            float ev[4];
#pragma unroll
            for (int a = 0; a < 4; ++a) ev[a] = Es[ib + a][jj];
#pragma unroll
            for (int a = 0; a < 4; ++a) {
                acc[a][0] = fmaf(ev[a], vv.x, acc[a][0]);
                acc[a][1] = fmaf(ev[a], vv.y, acc[a][1]);
                acc[a][2] = fmaf(ev[a], vv.z, acc[a][2]);
                acc[a][3] = fmaf(ev[a], vv.w, acc[a][3]);
            }
        }
    }

#pragma unroll
    for (int off = 1; off < 16; off <<= 1)
#pragma unroll
        for (int a = 0; a < 4; ++a)
            den[a] += __shfl_xor(den[a], off);

#pragma unroll
    for (int a = 0; a < 4; ++a) {
        const float inv = 1.0f / den[a];
        float4 o;
        o.x = acc[a][0] * inv; o.y = acc[a][1] * inv;
        o.z = acc[a][2] * inv; o.w = acc[a][3] * inv;
        const int l = i0 + ib + a;
        *(float4*)&ctx[(((size_t)(b * L_ + l)) * H_ + h) * DH_ + jb] = o;
    }
}

// ---------------------------------------------------------------------------
extern "C" void kernel_launch(void* const* d_in, const int* in_sizes, int n_in,
                              void* d_out, int out_size, void* d_ws, size_t ws_size,
                              hipStream_t stream)
{
    const float* x   = (const float*)d_in[0];
    const float* Wq  = (const float*)d_in[1];
    const float* bq  = (const float*)d_in[2];
    const float* Wk  = (const float*)d_in[3];
    const float* bk  = (const float*)d_in[4];
    const float* Wv  = (const float*)d_in[5];
    const float* bv  = (const float*)d_in[6];
    const float* Wo  = (const float*)d_in[7];
    const float* bo  = (const float*)d_in[8];
    const float* rel = (const float*)d_in[9];
    float* out = (float*)d_out;
    float* ws  = (float*)d_ws;

    const size_t HEADSZ = (size_t)B_ * H_ * L_ * DH_;  // 4,194,304 floats
    float* qw = ws;
    float* kw = ws + HEADSZ;
    float* vw = ws + 2 * HEADSZ;
    float* cw = ws + 3 * HEADSZ;

    // bf16 weights: wt_q/k/v overlap cw (cw written only later by attn_k);
    // wt_o overlaps qw, cast AFTER attn_k consumed qw. Total ws = 64 MB.
    short* wt_q = (short*)cw;
    short* wt_k = wt_q + (size_t)HID_ * HID_;
    short* wt_v = wt_k + (size_t)HID_ * HID_;
    short* wt_o = (short*)qw;

    const dim3 tb(256);
    const dim3 gw(16, 16);
    const dim3 gg(HID_ / 128, (B_ * L_) / 128);   // (8, 32)

    wcast_k<<<gw, tb, 0, stream>>>(Wq, wt_q);
    wcast_k<<<gw, tb, 0, stream>>>(Wk, wt_k);
    wcast_k<<<gw, tb, 0, stream>>>(Wv, wt_v);

    gemm_mfma_k<<<gg, tb, 0, stream>>>(x, wt_q, bq, qw, B_ * L_, HID_, HID_, 1);
    gemm_mfma_k<<<gg, tb, 0, stream>>>(x, wt_k, bk, kw, B_ * L_, HID_, HID_, 1);
    gemm_mfma_k<<<gg, tb, 0, stream>>>(x, wt_v, bv, vw, B_ * L_, HID_, HID_, 1);

    attn_k<<<dim3(L_ / 64, H_, B_), tb, 0, stream>>>(qw, kw, vw, rel, cw);

    wcast_k<<<gw, tb, 0, stream>>>(Wo, wt_o);
    gemm_mfma_k<<<gg, tb, 0, stream>>>(cw, wt_o, bo, out, B_ * L_, HID_, HID_, 0);
}

// Round 4
// 359.378 us; speedup vs baseline: 3.9606x; 2.8388x over previous
//
#include <hip/hip_runtime.h>
#include <cstddef>

#define B_ 4
#define L_ 1024
#define H_ 16
#define DH_ 64
#define HID_ 1024

typedef short bf16x8 __attribute__((ext_vector_type(8)));
typedef float f32x4  __attribute__((ext_vector_type(4)));

__device__ __forceinline__ short f2bf(float f) {
    unsigned u = __float_as_uint(f);
    u = (u + 0x7fffu + ((u >> 16) & 1u)) >> 16;   // RNE
    return (short)u;
}

// ---------------------------------------------------------------------------
// Transpose + cast: Wt[n][k] (bf16) = W[k][n] (f32).  64x64 tiles.
// ---------------------------------------------------------------------------
__global__ __launch_bounds__(256) void wcast_k(
    const float* __restrict__ W, short* __restrict__ Wt)
{
    __shared__ float T[64][65];
    const int t  = threadIdx.x;
    const int k0 = blockIdx.x << 6, n0 = blockIdx.y << 6;
    const int r  = t & 63;
    const int cg = t >> 6;
#pragma unroll
    for (int u = 0; u < 4; ++u) {
        float4 f = *(const float4*)&W[(size_t)(k0 + r) * HID_ + n0 + (cg << 4) + (u << 2)];
        T[r][(cg << 4) + (u << 2) + 0] = f.x;
        T[r][(cg << 4) + (u << 2) + 1] = f.y;
        T[r][(cg << 4) + (u << 2) + 2] = f.z;
        T[r][(cg << 4) + (u << 2) + 3] = f.w;
    }
    __syncthreads();
    bf16x8 p0, p1;
#pragma unroll
    for (int j = 0; j < 8; ++j) p0[j] = f2bf(T[(cg << 4) + j][r]);
#pragma unroll
    for (int j = 0; j < 8; ++j) p1[j] = f2bf(T[(cg << 4) + 8 + j][r]);
    short* dst = &Wt[(size_t)(n0 + r) * HID_ + k0 + (cg << 4)];
    *(bf16x8*)dst       = p0;
    *(bf16x8*)(dst + 8) = p1;
}

// ---------------------------------------------------------------------------
// rel_emb fp32 [2047][64] -> bf16
// ---------------------------------------------------------------------------
__global__ __launch_bounds__(256) void relcast_k(
    const float* __restrict__ rel, short* __restrict__ relb)
{
    const int gid  = blockIdx.x * 256 + threadIdx.x;
    const int base = gid << 3;
    if (base >= 2047 * 64) return;
    float4 f0 = *(const float4*)&rel[base];
    float4 f1 = *(const float4*)&rel[base + 4];
    bf16x8 p;
    p[0] = f2bf(f0.x); p[1] = f2bf(f0.y); p[2] = f2bf(f0.z); p[3] = f2bf(f0.w);
    p[4] = f2bf(f1.x); p[5] = f2bf(f1.y); p[6] = f2bf(f1.z); p[7] = f2bf(f1.w);
    *(bf16x8*)&relb[base] = p;
}

// ---------------------------------------------------------------------------
// bf16 MFMA GEMM: C = A(f32,[M,K]) @ Wt^T + bias  (Wt is [N,K] bf16).
// mode 0: fp32 C[m][n] flat.  mode 1: bf16 heads layout [B,H,L,DH].
// ---------------------------------------------------------------------------
__global__ __launch_bounds__(256) void gemm_mfma_k(
    const float* __restrict__ A, const short* __restrict__ Wt,
    const float* __restrict__ bias, void* __restrict__ Cout,
    int M, int N, int K, int mode)
{
    __shared__ short As[128 * 40];
    __shared__ short Bs[128 * 40];

    const int t    = threadIdx.x;
    const int m0   = blockIdx.y << 7, n0 = blockIdx.x << 7;
    const int lane = t & 63, wv = t >> 6;
    const int wm0  = (wv & 1) << 6, wn0 = (wv >> 1) << 6;
    const int fr   = lane & 15, quad = lane >> 4;

    const int sr = t >> 1;
    const int kh = (t & 1) << 4;

    f32x4 acc[4][4];
#pragma unroll
    for (int i = 0; i < 4; ++i)
#pragma unroll
        for (int j = 0; j < 4; ++j) acc[i][j] = (f32x4){0.f, 0.f, 0.f, 0.f};

    const float* aptr = A  + (size_t)(m0 + sr) * K + kh;
    const short* bptr = Wt + (size_t)(n0 + sr) * K + kh;

    for (int k0 = 0; k0 < K; k0 += 32) {
        float4 a0 = *(const float4*)(aptr + k0);
        float4 a1 = *(const float4*)(aptr + k0 + 4);
        float4 a2 = *(const float4*)(aptr + k0 + 8);
        float4 a3 = *(const float4*)(aptr + k0 + 12);
        bf16x8 w0 = *(const bf16x8*)(bptr + k0);
        bf16x8 w1 = *(const bf16x8*)(bptr + k0 + 8);

        __syncthreads();
        bf16x8 p0, p1;
        p0[0] = f2bf(a0.x); p0[1] = f2bf(a0.y); p0[2] = f2bf(a0.z); p0[3] = f2bf(a0.w);
        p0[4] = f2bf(a1.x); p0[5] = f2bf(a1.y); p0[6] = f2bf(a1.z); p0[7] = f2bf(a1.w);
        p1[0] = f2bf(a2.x); p1[1] = f2bf(a2.y); p1[2] = f2bf(a2.z); p1[3] = f2bf(a2.w);
        p1[4] = f2bf(a3.x); p1[5] = f2bf(a3.y); p1[6] = f2bf(a3.z); p1[7] = f2bf(a3.w);
        *(bf16x8*)&As[sr * 40 + kh]     = p0;
        *(bf16x8*)&As[sr * 40 + kh + 8] = p1;
        *(bf16x8*)&Bs[sr * 40 + kh]     = w0;
        *(bf16x8*)&Bs[sr * 40 + kh + 8] = w1;
        __syncthreads();

        bf16x8 af[4], bfv[4];
#pragma unroll
        for (int mt = 0; mt < 4; ++mt)
            af[mt] = *(const bf16x8*)&As[(wm0 + (mt << 4) + fr) * 40 + (quad << 3)];
#pragma unroll
        for (int nt = 0; nt < 4; ++nt)
            bfv[nt] = *(const bf16x8*)&Bs[(wn0 + (nt << 4) + fr) * 40 + (quad << 3)];
#pragma unroll
        for (int mt = 0; mt < 4; ++mt)
#pragma unroll
            for (int nt = 0; nt < 4; ++nt)
                acc[mt][nt] = __builtin_amdgcn_mfma_f32_16x16x32_bf16(
                    af[mt], bfv[nt], acc[mt][nt], 0, 0, 0);
    }

    float bv[4];
#pragma unroll
    for (int nt = 0; nt < 4; ++nt) bv[nt] = bias[n0 + wn0 + (nt << 4) + fr];

#pragma unroll
    for (int mt = 0; mt < 4; ++mt)
#pragma unroll
        for (int nt = 0; nt < 4; ++nt)
#pragma unroll
            for (int r = 0; r < 4; ++r) {
                const int row  = m0 + wm0 + (mt << 4) + (quad << 2) + r;
                const int coln = n0 + wn0 + (nt << 4) + fr;
                const float val = acc[mt][nt][r] + bv[nt];
                if (mode == 0) {
                    ((float*)Cout)[(size_t)row * N + coln] = val;
                } else {
                    const int b = row >> 10, l = row & 1023;
                    const int h = coln >> 6, d = coln & 63;
                    ((short*)Cout)[(((size_t)(b * H_ + h) << 10) + l) * DH_ + d] = f2bf(val);
                }
            }
}

// ---------------------------------------------------------------------------
// MFMA attention. Per block: one (b,h,64-row Q tile). 4 waves, wave w owns
// S/O rows [16w,16w+16). Per 64-col j-tile: QK (8 mfma) + T=Q@relband^T (16)
// + exp/gather + PV (8). LDS XOR-swizzled stride-64 tiles; Ts stride 130.
// Ps aliases Rs (safe: barrier after T-MFMAs). Total LDS 74240 B -> 2 blk/CU.
// ---------------------------------------------------------------------------
__global__ __launch_bounds__(256, 2) void attn_mfma_k(
    const short* __restrict__ q, const short* __restrict__ k,
    const short* __restrict__ v, const short* __restrict__ relb,
    float* __restrict__ ctx)
{
    __shared__ __align__(16) short Qs[64 * 64];
    __shared__ __align__(16) short Ks[64 * 64];
    __shared__ __align__(16) short Vt[64 * 64];   // V^T: [d][j]
    __shared__ __align__(16) short Rs[128 * 64];  // rel band; Ps aliases rows 0..63
    __shared__ float Ts[64 * 130];                // T[ii][r], stride 130

    const int t  = threadIdx.x;
    const int i0 = blockIdx.x << 6;
    const int h  = blockIdx.y;
    const int b  = blockIdx.z;
    const size_t bh = (size_t)(b * H_ + h) << 16;   // * L*DH

    const int lane = t & 63;
    const int w    = t >> 6;
    const int fr   = lane & 15;
    const int qd   = lane >> 4;

    {   // stage Q once (swizzled: group g at slot g^(row&7))
        const int r  = t >> 2;
        const int g0 = (t & 3) << 1;
#pragma unroll
        for (int u = 0; u < 2; ++u) {
            const int g = g0 + u;
            *(bf16x8*)&Qs[(r << 6) + ((g ^ (r & 7)) << 3)] =
                *(const bf16x8*)&q[bh + ((size_t)(i0 + r) << 6) + (g << 3)];
        }
    }

    f32x4 acc_o[4];
#pragma unroll
    for (int i = 0; i < 4; ++i) acc_o[i] = (f32x4){0.f, 0.f, 0.f, 0.f};
    float den[4] = {0.f, 0.f, 0.f, 0.f};

    for (int j0 = 0; j0 < L_; j0 += 64) {
        __syncthreads();   // all prev-iter LDS reads complete
        {   // stage K
            const int r  = t >> 2;
            const int g0 = (t & 3) << 1;
#pragma unroll
            for (int u = 0; u < 2; ++u) {
                const int g = g0 + u;
                *(bf16x8*)&Ks[(r << 6) + ((g ^ (r & 7)) << 3)] =
                    *(const bf16x8*)&k[bh + ((size_t)(j0 + r) << 6) + (g << 3)];
            }
        }
        {   // stage V transposed: Vt[d][j]
            const int j  = t & 63;
            const int d0 = (t >> 6) << 4;
            bf16x8 v0 = *(const bf16x8*)&v[bh + ((size_t)(j0 + j) << 6) + d0];
            bf16x8 v1 = *(const bf16x8*)&v[bh + ((size_t)(j0 + j) << 6) + d0 + 8];
#pragma unroll
            for (int u = 0; u < 8; ++u) {
                const int d = d0 + u;
                Vt[(d << 6) + (((j >> 3) ^ (d & 7)) << 3) + (j & 7)] = v0[u];
            }
#pragma unroll
            for (int u = 0; u < 8; ++u) {
                const int d = d0 + 8 + u;
                Vt[(d << 6) + (((j >> 3) ^ (d & 7)) << 3) + (j & 7)] = v1[u];
            }
        }
        {   // stage rel band rows rbase..rbase+127 (row 127 clamped, unused)
            const int rbase = i0 - j0 + 960;
            const int rr = t >> 1;
            const int g0 = (t & 1) << 2;
            const int grow = min(rbase + rr, 2046);
#pragma unroll
            for (int u = 0; u < 4; ++u) {
                const int g = g0 + u;
                *(bf16x8*)&Rs[(rr << 6) + ((g ^ (rr & 7)) << 3)] =
                    *(const bf16x8*)&relb[((size_t)grow << 6) + (g << 3)];
            }
        }
        __syncthreads();

        f32x4 acc_s[4], acc_t[8];
#pragma unroll
        for (int i = 0; i < 4; ++i) acc_s[i] = (f32x4){0.f, 0.f, 0.f, 0.f};
#pragma unroll
        for (int i = 0; i < 8; ++i) acc_t[i] = (f32x4){0.f, 0.f, 0.f, 0.f};

#pragma unroll
        for (int hh = 0; hh < 2; ++hh) {
            const int g  = (hh << 2) + qd;
            const int ra = (w << 4) + fr;
            bf16x8 af = *(const bf16x8*)&Qs[(ra << 6) + ((g ^ (ra & 7)) << 3)];
#pragma unroll
            for (int nt = 0; nt < 4; ++nt) {
                const int rb = (nt << 4) + fr;
                bf16x8 bk = *(const bf16x8*)&Ks[(rb << 6) + ((g ^ (rb & 7)) << 3)];
                acc_s[nt] = __builtin_amdgcn_mfma_f32_16x16x32_bf16(af, bk, acc_s[nt], 0, 0, 0);
            }
#pragma unroll
            for (int rt = 0; rt < 8; ++rt) {
                const int rb = (rt << 4) + fr;
                bf16x8 br = *(const bf16x8*)&Rs[(rb << 6) + ((g ^ (rb & 7)) << 3)];
                acc_t[rt] = __builtin_amdgcn_mfma_f32_16x16x32_bf16(af, br, acc_t[rt], 0, 0, 0);
            }
        }

        const int iiB = (w << 4) + (qd << 2);   // lane's 4 C rows
#pragma unroll
        for (int rt = 0; rt < 8; ++rt)
#pragma unroll
            for (int rg = 0; rg < 4; ++rg)
                Ts[(iiB + rg) * 130 + (rt << 4) + fr] = acc_t[rt][rg];
        __syncthreads();   // all Rs reads (T MFMAs) done before Ps overwrite

        // exp + diagonal gather + P -> LDS (bf16, A-operand layout)
#pragma unroll
        for (int nt = 0; nt < 4; ++nt) {
            const int jj = (nt << 4) + fr;
#pragma unroll
            for (int rg = 0; rg < 4; ++rg) {
                const int ii = iiB + rg;
                float s = acc_s[nt][rg] * 0.125f;
                s = fminf(fmaxf(s, -100000.f), 100000.f);
                const float e = __expf(s + Ts[ii * 130 + ii - jj + 63]);
                den[rg] += e;
                Rs[(ii << 6) + (((jj >> 3) ^ (ii & 7)) << 3) + (jj & 7)] = f2bf(e);
            }
        }
        // no barrier: Ps/Ts consumed intra-wave only

#pragma unroll
        for (int hh = 0; hh < 2; ++hh) {
            const int g  = (hh << 2) + qd;
            const int ra = (w << 4) + fr;
            bf16x8 ap = *(const bf16x8*)&Rs[(ra << 6) + ((g ^ (ra & 7)) << 3)];
#pragma unroll
            for (int nt = 0; nt < 4; ++nt) {
                const int rb = (nt << 4) + fr;
                bf16x8 bv = *(const bf16x8*)&Vt[(rb << 6) + ((g ^ (rb & 7)) << 3)];
                acc_o[nt] = __builtin_amdgcn_mfma_f32_16x16x32_bf16(ap, bv, acc_o[nt], 0, 0, 0);
            }
        }
    }

#pragma unroll
    for (int off = 1; off < 16; off <<= 1)
#pragma unroll
        for (int rg = 0; rg < 4; ++rg)
            den[rg] += __shfl_xor(den[rg], off);

    const int iiB = (w << 4) + (qd << 2);
#pragma unroll
    for (int rg = 0; rg < 4; ++rg) {
        const float inv = 1.0f / den[rg];
        const int l = i0 + iiB + rg;
#pragma unroll
        for (int nt = 0; nt < 4; ++nt)
            ctx[(((size_t)(b * L_ + l)) * H_ + h) * DH_ + (nt << 4) + fr] =
                acc_o[nt][rg] * inv;
    }
}

// ---------------------------------------------------------------------------
extern "C" void kernel_launch(void* const* d_in, const int* in_sizes, int n_in,
                              void* d_out, int out_size, void* d_ws, size_t ws_size,
                              hipStream_t stream)
{
    const float* x   = (const float*)d_in[0];
    const float* Wq  = (const float*)d_in[1];
    const float* bq  = (const float*)d_in[2];
    const float* Wk  = (const float*)d_in[3];
    const float* bk  = (const float*)d_in[4];
    const float* Wv  = (const float*)d_in[5];
    const float* bv  = (const float*)d_in[6];
    const float* Wo  = (const float*)d_in[7];
    const float* bo  = (const float*)d_in[8];
    const float* rel = (const float*)d_in[9];
    float* out = (float*)d_out;

    const size_t HEADSZ = (size_t)B_ * H_ * L_ * DH_;   // 4,194,304
    short* qw   = (short*)d_ws;
    short* kw   = qw + HEADSZ;
    short* vw   = kw + HEADSZ;
    float* cw   = (float*)(vw + HEADSZ);                // fp32 [B,L,H*DH]
    short* wt_q = (short*)(cw + HEADSZ);
    short* wt_k = wt_q + (size_t)HID_ * HID_;
    short* wt_v = wt_k + (size_t)HID_ * HID_;
    short* wt_o = wt_v + (size_t)HID_ * HID_;
    short* relb = wt_o + (size_t)HID_ * HID_;           // 2047*64 bf16

    const dim3 tb(256);
    const dim3 gw(16, 16);
    const dim3 gg(HID_ / 128, (B_ * L_) / 128);

    wcast_k<<<gw, tb, 0, stream>>>(Wq, wt_q);
    wcast_k<<<gw, tb, 0, stream>>>(Wk, wt_k);
    wcast_k<<<gw, tb, 0, stream>>>(Wv, wt_v);
    wcast_k<<<gw, tb, 0, stream>>>(Wo, wt_o);
    relcast_k<<<dim3(64), tb, 0, stream>>>(rel, relb);

    gemm_mfma_k<<<gg, tb, 0, stream>>>(x, wt_q, bq, qw, B_ * L_, HID_, HID_, 1);
    gemm_mfma_k<<<gg, tb, 0, stream>>>(x, wt_k, bk, kw, B_ * L_, HID_, HID_, 1);
    gemm_mfma_k<<<gg, tb, 0, stream>>>(x, wt_v, bv, vw, B_ * L_, HID_, HID_, 1);

    attn_mfma_k<<<dim3(L_ / 64, H_, B_), tb, 0, stream>>>(qw, kw, vw, relb, cw);

    gemm_mfma_k<<<gg, tb, 0, stream>>>(cw, wt_o, bo, out, B_ * L_, HID_, HID_, 0);
}

// Round 5
// 315.185 us; speedup vs baseline: 4.5159x; 1.1402x over previous
//
#include <hip/hip_runtime.h>
#include <cstddef>

#define B_ 4
#define L_ 1024
#define H_ 16
#define DH_ 64
#define HID_ 1024
#define HEADSZ_ 4194304   // B*H*L*DH

typedef short bf16x8 __attribute__((ext_vector_type(8)));
typedef float f32x4  __attribute__((ext_vector_type(4)));

__device__ __forceinline__ short f2bf(float f) {
    unsigned u = __float_as_uint(f);
    u = (u + 0x7fffu + ((u >> 16) & 1u)) >> 16;   // RNE
    return (short)u;
}

__device__ __forceinline__ void glds16(const short* g, short* l) {
    __builtin_amdgcn_global_load_lds(
        (const __attribute__((address_space(1))) unsigned int*)g,
        (__attribute__((address_space(3))) unsigned int*)l, 16, 0, 0);
}

// ---------------------------------------------------------------------------
// x fp32 -> bf16 (4096x1024)
// ---------------------------------------------------------------------------
__global__ __launch_bounds__(256) void xcast_k(
    const float* __restrict__ x, short* __restrict__ xb)
{
    const int base = (blockIdx.x * 256 + threadIdx.x) << 3;
    float4 f0 = *(const float4*)&x[base];
    float4 f1 = *(const float4*)&x[base + 4];
    bf16x8 p;
    p[0] = f2bf(f0.x); p[1] = f2bf(f0.y); p[2] = f2bf(f0.z); p[3] = f2bf(f0.w);
    p[4] = f2bf(f1.x); p[5] = f2bf(f1.y); p[6] = f2bf(f1.z); p[7] = f2bf(f1.w);
    *(bf16x8*)&xb[base] = p;
}

// ---------------------------------------------------------------------------
// 4 weights: transpose + cast Wt[n][k] = W[k][n], z selects the weight.
// ---------------------------------------------------------------------------
__global__ __launch_bounds__(256) void wcast4_k(
    const float* __restrict__ Wq, const float* __restrict__ Wk,
    const float* __restrict__ Wv, const float* __restrict__ Wo,
    short* __restrict__ Wt)
{
    const float* W = (blockIdx.z == 0) ? Wq : (blockIdx.z == 1) ? Wk
                   : (blockIdx.z == 2) ? Wv : Wo;
    short* dstb = Wt + (size_t)blockIdx.z * HID_ * HID_;
    __shared__ float T[64][65];
    const int t  = threadIdx.x;
    const int k0 = blockIdx.x << 6, n0 = blockIdx.y << 6;
    const int r  = t & 63;
    const int cg = t >> 6;
#pragma unroll
    for (int u = 0; u < 4; ++u) {
        float4 f = *(const float4*)&W[(size_t)(k0 + r) * HID_ + n0 + (cg << 4) + (u << 2)];
        T[r][(cg << 4) + (u << 2) + 0] = f.x;
        T[r][(cg << 4) + (u << 2) + 1] = f.y;
        T[r][(cg << 4) + (u << 2) + 2] = f.z;
        T[r][(cg << 4) + (u << 2) + 3] = f.w;
    }
    __syncthreads();
    bf16x8 p0, p1;
#pragma unroll
    for (int j = 0; j < 8; ++j) p0[j] = f2bf(T[(cg << 4) + j][r]);
#pragma unroll
    for (int j = 0; j < 8; ++j) p1[j] = f2bf(T[(cg << 4) + 8 + j][r]);
    short* dst = &dstb[(size_t)(n0 + r) * HID_ + k0 + (cg << 4)];
    *(bf16x8*)dst       = p0;
    *(bf16x8*)(dst + 8) = p1;
}

// ---------------------------------------------------------------------------
// rel_emb fp32 [2047][64] -> bf16
// ---------------------------------------------------------------------------
__global__ __launch_bounds__(256) void relcast_k(
    const float* __restrict__ rel, short* __restrict__ relb)
{
    const int base = (blockIdx.x * 256 + threadIdx.x) << 3;
    if (base >= 2047 * 64) return;
    float4 f0 = *(const float4*)&rel[base];
    float4 f1 = *(const float4*)&rel[base + 4];
    bf16x8 p;
    p[0] = f2bf(f0.x); p[1] = f2bf(f0.y); p[2] = f2bf(f0.z); p[3] = f2bf(f0.w);
    p[4] = f2bf(f1.x); p[5] = f2bf(f1.y); p[6] = f2bf(f1.z); p[7] = f2bf(f1.w);
    *(bf16x8*)&relb[base] = p;
}

// ---------------------------------------------------------------------------
// m97-style bf16 GEMM with global_load_lds staging. Tile 128 x (NT*32),
// BK=32, 256 thr = 4 waves (2x2), wave quadrant 64 x (NT*16).
// mode 0: fp32 out[row*1024+coln] (bias b0)
// mode 1: bf16 qkv heads layout; tensor 2 (v) written TRANSPOSED [b,h,d,l].
// ---------------------------------------------------------------------------
template <int NT>
__global__ __launch_bounds__(256, 2) void gemm_glds_k(
    const short* __restrict__ A, const short* __restrict__ Wt,
    const float* __restrict__ b0, const float* __restrict__ b1,
    const float* __restrict__ b2, void* __restrict__ outv,
    int K, int mode)
{
    constexpr int BN = NT * 32;
    __shared__ short As[128 * 32];
    __shared__ short Bs[BN * 32];

    const int t    = threadIdx.x;
    const int lane = t & 63, w = t >> 6;
    const int m0   = blockIdx.y << 7, n0 = blockIdx.x * BN;
    const int fr   = lane & 15, qd = lane >> 4;
    const int wm0  = (w & 1) << 6, wn0 = (w >> 1) * (NT << 4);

    f32x4 acc[4][NT];
#pragma unroll
    for (int i = 0; i < 4; ++i)
#pragma unroll
        for (int j = 0; j < NT; ++j) acc[i][j] = (f32x4){0.f, 0.f, 0.f, 0.f};

    const short* aSrc = A  + (size_t)(m0 + w * 32 + (lane >> 2)) * K + (lane & 3) * 8;
    const short* bSrc = Wt + (size_t)(n0 + w * (BN / 4) + (lane >> 2)) * K + (lane & 3) * 8;
    short* aDst0 = &As[(w * 32) * 32];
    short* aDst1 = &As[(w * 32 + 16) * 32];
    short* bDst0 = &Bs[(w * (BN / 4)) * 32];
    short* bDst1 = &Bs[(w * (BN / 4) + 16) * 32];

    for (int k0 = 0; k0 < K; k0 += 32) {
        __syncthreads();
        glds16(aSrc + k0, aDst0);
        glds16(aSrc + (size_t)16 * K + k0, aDst1);
        glds16(bSrc + k0, bDst0);
        if (NT == 4) glds16(bSrc + (size_t)16 * K + k0, bDst1);
        __syncthreads();

        bf16x8 af[4], bfv[NT];
#pragma unroll
        for (int mt = 0; mt < 4; ++mt)
            af[mt] = *(const bf16x8*)&As[(wm0 + (mt << 4) + fr) * 32 + (qd << 3)];
#pragma unroll
        for (int nt = 0; nt < NT; ++nt)
            bfv[nt] = *(const bf16x8*)&Bs[(wn0 + (nt << 4) + fr) * 32 + (qd << 3)];
#pragma unroll
        for (int mt = 0; mt < 4; ++mt)
#pragma unroll
            for (int nt = 0; nt < NT; ++nt)
                acc[mt][nt] = __builtin_amdgcn_mfma_f32_16x16x32_bf16(
                    af[mt], bfv[nt], acc[mt][nt], 0, 0, 0);
    }

#pragma unroll
    for (int nt = 0; nt < NT; ++nt) {
        const int coln = n0 + wn0 + (nt << 4) + fr;
        float bias;
        if (mode == 0) bias = b0[coln];
        else {
            const int t3 = coln >> 10;
            bias = (t3 == 0 ? b0 : t3 == 1 ? b1 : b2)[coln & 1023];
        }
#pragma unroll
        for (int mt = 0; mt < 4; ++mt)
#pragma unroll
            for (int rg = 0; rg < 4; ++rg) {
                const int row = m0 + wm0 + (mt << 4) + (qd << 2) + rg;
                const float val = acc[mt][nt][rg] + bias;
                if (mode == 0) {
                    ((float*)outv)[(size_t)row * HID_ + coln] = val;
                } else {
                    const int t3 = coln >> 10;
                    const int h  = (coln >> 6) & 15;
                    const int d  = coln & 63;
                    const int bb = row >> 10, l = row & 1023;
                    size_t dst;
                    if (t3 == 2)   // V transposed: [b,h,d,l]
                        dst = (size_t)t3 * HEADSZ_ + ((((size_t)(bb * H_ + h)) << 6) + d) * 1024 + l;
                    else
                        dst = (size_t)t3 * HEADSZ_ + ((((size_t)(bb * H_ + h)) << 10) + l) * 64 + d;
                    ((short*)outv)[dst] = f2bf(val);
                }
            }
    }
}

// ---------------------------------------------------------------------------
// MFMA attention, LDS-minimal. Per block: (b, h, 64-row Q tile), 4 waves.
// Q A-frags hoisted to regs (direct global). K and rel B-frags direct from
// global (L2). Rolling T: one new 64-row rel chunk per j-tile, Ts[2][64][68]
// fp32 double-buffer (wave-private). V pre-transposed in global [b,h,d,l],
// staged to LDS (only cross-wave tile -> 2 barriers/tile). P round-trip via
// Ps[64][72] (wave-private). LDS = 52 KB -> 3 blocks/CU.
// ---------------------------------------------------------------------------
__global__ __launch_bounds__(256, 3) void attn_mfma_k(
    const short* __restrict__ q, const short* __restrict__ k,
    const short* __restrict__ vT, const short* __restrict__ relb,
    short* __restrict__ ctx)
{
    __shared__ __align__(16) short Vt[64 * 72];
    __shared__ __align__(16) short Ps[64 * 72];
    __shared__ __align__(16) float Ts[128 * 68];

    const int t    = threadIdx.x;
    const int i0   = blockIdx.x << 6;
    const int h    = blockIdx.y;
    const int b    = blockIdx.z;
    const size_t bh = (size_t)(b * H_ + h) << 16;
    const int lane = t & 63, w = t >> 6;
    const int fr   = lane & 15, qd = lane >> 4;
    const int m16  = i0 >> 6;

    // Q A-fragments, loaded once from global
    bf16x8 af[2];
#pragma unroll
    for (int hh = 0; hh < 2; ++hh)
        af[hh] = *(const bf16x8*)&q[bh + ((size_t)(i0 + (w << 4) + fr) << 6)
                                    + (((hh << 2) + qd) << 3)];

    // prologue: T for upper chunk m16+16, parity (m16+16)&1 == m16&1
    {
        f32x4 acc_t[4];
#pragma unroll
        for (int i = 0; i < 4; ++i) acc_t[i] = (f32x4){0.f, 0.f, 0.f, 0.f};
#pragma unroll
        for (int hh = 0; hh < 2; ++hh)
#pragma unroll
            for (int rt = 0; rt < 4; ++rt) {
                const int row = min(((m16 + 16) << 6) + (rt << 4) + fr, 2046);
                bf16x8 br = *(const bf16x8*)&relb[((size_t)row << 6) + (((hh << 2) + qd) << 3)];
                acc_t[rt] = __builtin_amdgcn_mfma_f32_16x16x32_bf16(af[hh], br, acc_t[rt], 0, 0, 0);
            }
        const int pu = m16 & 1;
#pragma unroll
        for (int rt = 0; rt < 4; ++rt)
            *(f32x4*)&Ts[((pu << 6) + (rt << 4) + fr) * 68 + (w << 4) + (qd << 2)] = acc_t[rt];
    }

    f32x4 acc_o[4];
#pragma unroll
    for (int i = 0; i < 4; ++i) acc_o[i] = (f32x4){0.f, 0.f, 0.f, 0.f};
    float den[4] = {0.f, 0.f, 0.f, 0.f};

    for (int jt = 0; jt < 16; ++jt) {
        const int j0 = jt << 6;
        __syncthreads();   // prev tile's Vt reads done
        {   // stage V^T tile: Vt[d][j], stride 72
            const int d  = t >> 2;
            const int g0 = (t & 3) << 4;
            const short* src = &vT[bh + ((size_t)d << 10) + j0 + g0];
            bf16x8 v0 = *(const bf16x8*)src;
            bf16x8 v1 = *(const bf16x8*)(src + 8);
            *(bf16x8*)&Vt[d * 72 + g0]     = v0;
            *(bf16x8*)&Vt[d * 72 + g0 + 8] = v1;
        }
        __syncthreads();   // Vt visible

        // S = Q K^T  (K B-frags direct from global)
        f32x4 acc_s[4];
#pragma unroll
        for (int i = 0; i < 4; ++i) acc_s[i] = (f32x4){0.f, 0.f, 0.f, 0.f};
#pragma unroll
        for (int hh = 0; hh < 2; ++hh)
#pragma unroll
            for (int nt = 0; nt < 4; ++nt) {
                bf16x8 bk = *(const bf16x8*)&k[bh + ((size_t)(j0 + (nt << 4) + fr) << 6)
                                              + (((hh << 2) + qd) << 3)];
                acc_s[nt] = __builtin_amdgcn_mfma_f32_16x16x32_bf16(af[hh], bk, acc_s[nt], 0, 0, 0);
            }

        // new T chunk m_low = m16 + 15 - jt  (rel B-frags direct from global)
        const int mlow = m16 + 15 - jt;
        const int pl   = mlow & 1;
        {
            f32x4 acc_t[4];
#pragma unroll
            for (int i = 0; i < 4; ++i) acc_t[i] = (f32x4){0.f, 0.f, 0.f, 0.f};
#pragma unroll
            for (int hh = 0; hh < 2; ++hh)
#pragma unroll
                for (int rt = 0; rt < 4; ++rt) {
                    const int row = (mlow << 6) + (rt << 4) + fr;   // <= 1983+63 < 2047
                    bf16x8 br = *(const bf16x8*)&relb[((size_t)row << 6) + (((hh << 2) + qd) << 3)];
                    acc_t[rt] = __builtin_amdgcn_mfma_f32_16x16x32_bf16(af[hh], br, acc_t[rt], 0, 0, 0);
                }
#pragma unroll
            for (int rt = 0; rt < 4; ++rt)
                *(f32x4*)&Ts[((pl << 6) + (rt << 4) + fr) * 68 + (w << 4) + (qd << 2)] = acc_t[rt];
        }
        // Ts/Ps are wave-private: intra-wave lgkmcnt ordering suffices.

        // exp + diagonal T gather + P -> LDS (A-operand layout, stride 72)
#pragma unroll
        for (int nt = 0; nt < 4; ++nt) {
            const int jj = (nt << 4) + fr;
#pragma unroll
            for (int rg = 0; rg < 4; ++rg) {
                const int ii = (w << 4) + (qd << 2) + rg;
                const int r7 = ii - jj + 63;                       // [0,126]
                const int trow = ((pl ^ (r7 >> 6)) << 6) + (r7 & 63);
                const float tv = Ts[trow * 68 + ii];
                float s = acc_s[nt][rg] * 0.125f;
                s = fminf(fmaxf(s, -100000.f), 100000.f);
                const float e = __expf(s + tv);
                den[rg] += e;
                Ps[ii * 72 + jj] = f2bf(e);
            }
        }

        // O += P V   (A from Ps intra-wave, B from Vt)
#pragma unroll
        for (int hh = 0; hh < 2; ++hh) {
            bf16x8 ap = *(const bf16x8*)&Ps[((w << 4) + fr) * 72 + (((hh << 2) + qd) << 3)];
#pragma unroll
            for (int nt = 0; nt < 4; ++nt) {
                bf16x8 bv = *(const bf16x8*)&Vt[((nt << 4) + fr) * 72 + (((hh << 2) + qd) << 3)];
                acc_o[nt] = __builtin_amdgcn_mfma_f32_16x16x32_bf16(ap, bv, acc_o[nt], 0, 0, 0);
            }
        }
    }

#pragma unroll
    for (int off = 1; off < 16; off <<= 1)
#pragma unroll
        for (int rg = 0; rg < 4; ++rg)
            den[rg] += __shfl_xor(den[rg], off);

#pragma unroll
    for (int rg = 0; rg < 4; ++rg) {
        const float inv = 1.0f / den[rg];
        const int l = i0 + (w << 4) + (qd << 2) + rg;
#pragma unroll
        for (int nt = 0; nt < 4; ++nt)
            ctx[((size_t)(b * L_ + l) << 10) + (h << 6) + (nt << 4) + fr] =
                f2bf(acc_o[nt][rg] * inv);
    }
}

// ---------------------------------------------------------------------------
extern "C" void kernel_launch(void* const* d_in, const int* in_sizes, int n_in,
                              void* d_out, int out_size, void* d_ws, size_t ws_size,
                              hipStream_t stream)
{
    const float* x   = (const float*)d_in[0];
    const float* Wq  = (const float*)d_in[1];
    const float* bq  = (const float*)d_in[2];
    const float* Wk  = (const float*)d_in[3];
    const float* bk  = (const float*)d_in[4];
    const float* Wv  = (const float*)d_in[5];
    const float* bv  = (const float*)d_in[6];
    const float* Wo  = (const float*)d_in[7];
    const float* bo  = (const float*)d_in[8];
    const float* rel = (const float*)d_in[9];
    float* out = (float*)d_out;

    short* xb   = (short*)d_ws;                         // 4096x1024 bf16
    short* qkv  = xb + (size_t)HEADSZ_;                 // q,k,v(T) bf16 (3x)
    short* cw   = qkv + (size_t)3 * HEADSZ_;            // ctx bf16 [B*L, HID]
    short* wt   = cw + (size_t)HEADSZ_;                 // 4 x HID^2 bf16
    short* relb = wt + (size_t)4 * HID_ * HID_;         // 2047*64 bf16

    const dim3 tb(256);

    xcast_k<<<dim3(2048), tb, 0, stream>>>(x, xb);
    wcast4_k<<<dim3(16, 16, 4), tb, 0, stream>>>(Wq, Wk, Wv, Wo, wt);
    relcast_k<<<dim3(64), tb, 0, stream>>>(rel, relb);

    // fused QKV GEMM: N=3072, tile 128x128
    gemm_glds_k<4><<<dim3(24, 32), tb, 0, stream>>>(
        xb, wt, bq, bk, bv, qkv, HID_, 1);

    attn_mfma_k<<<dim3(16, H_, B_), tb, 0, stream>>>(
        qkv, qkv + HEADSZ_, qkv + 2 * (size_t)HEADSZ_, relb, cw);

    // output GEMM: N=1024, tile 128x64
    gemm_glds_k<2><<<dim3(16, 32), tb, 0, stream>>>(
        cw, wt + (size_t)3 * HID_ * HID_, bo, bo, bo, out, HID_, 0);
}

// Round 6
// 224.711 us; speedup vs baseline: 6.3342x; 1.4026x over previous
//
#include <hip/hip_runtime.h>
#include <cstddef>

#define B_ 4
#define L_ 1024
#define H_ 16
#define DH_ 64
#define HID_ 1024
#define HEADSZ_ 4194304   // B*H*L*DH

typedef short bf16x8 __attribute__((ext_vector_type(8)));
typedef short bf16x4 __attribute__((ext_vector_type(4)));
typedef float f32x4  __attribute__((ext_vector_type(4)));

__device__ __forceinline__ short f2bf(float f) {
    unsigned u = __float_as_uint(f);
    u = (u + 0x7fffu + ((u >> 16) & 1u)) >> 16;   // RNE
    return (short)u;
}
__device__ __forceinline__ float bf2f(short s) {
    return __uint_as_float(((unsigned)(unsigned short)s) << 16);
}
__device__ __forceinline__ void glds16(const short* g, short* l) {
    __builtin_amdgcn_global_load_lds(
        (const __attribute__((address_space(1))) unsigned int*)g,
        (__attribute__((address_space(3))) unsigned int*)l, 16, 0, 0);
}

// ---------------------------------------------------------------------------
// x fp32 -> bf16 (4096x1024)
// ---------------------------------------------------------------------------
__global__ __launch_bounds__(256) void xcast_k(
    const float* __restrict__ x, short* __restrict__ xb)
{
    const int base = (blockIdx.x * 256 + threadIdx.x) << 3;
    float4 f0 = *(const float4*)&x[base];
    float4 f1 = *(const float4*)&x[base + 4];
    bf16x8 p;
    p[0] = f2bf(f0.x); p[1] = f2bf(f0.y); p[2] = f2bf(f0.z); p[3] = f2bf(f0.w);
    p[4] = f2bf(f1.x); p[5] = f2bf(f1.y); p[6] = f2bf(f1.z); p[7] = f2bf(f1.w);
    *(bf16x8*)&xb[base] = p;
}

// ---------------------------------------------------------------------------
// 4 weights: transpose + cast Wt[n][k] = W[k][n], z selects the weight.
// ---------------------------------------------------------------------------
__global__ __launch_bounds__(256) void wcast4_k(
    const float* __restrict__ Wq, const float* __restrict__ Wk,
    const float* __restrict__ Wv, const float* __restrict__ Wo,
    short* __restrict__ Wt)
{
    const float* W = (blockIdx.z == 0) ? Wq : (blockIdx.z == 1) ? Wk
                   : (blockIdx.z == 2) ? Wv : Wo;
    short* dstb = Wt + (size_t)blockIdx.z * HID_ * HID_;
    __shared__ float T[64][65];
    const int t  = threadIdx.x;
    const int k0 = blockIdx.x << 6, n0 = blockIdx.y << 6;
    const int r  = t & 63;
    const int cg = t >> 6;
#pragma unroll
    for (int u = 0; u < 4; ++u) {
        float4 f = *(const float4*)&W[(size_t)(k0 + r) * HID_ + n0 + (cg << 4) + (u << 2)];
        T[r][(cg << 4) + (u << 2) + 0] = f.x;
        T[r][(cg << 4) + (u << 2) + 1] = f.y;
        T[r][(cg << 4) + (u << 2) + 2] = f.z;
        T[r][(cg << 4) + (u << 2) + 3] = f.w;
    }
    __syncthreads();
    bf16x8 p0, p1;
#pragma unroll
    for (int j = 0; j < 8; ++j) p0[j] = f2bf(T[(cg << 4) + j][r]);
#pragma unroll
    for (int j = 0; j < 8; ++j) p1[j] = f2bf(T[(cg << 4) + 8 + j][r]);
    short* dst = &dstb[(size_t)(n0 + r) * HID_ + k0 + (cg << 4)];
    *(bf16x8*)dst       = p0;
    *(bf16x8*)(dst + 8) = p1;
}

// ---------------------------------------------------------------------------
// rel_emb fp32 [2047][64] -> 32 swizzled 8KB chunk images (bf16).
// chunk m holds rows 64m..64m+63; element (r,d) at
//   m*4096 + (r&63)*64 + (((d>>3) ^ (r&7))<<3) + (d&7)
// (row 2047 of chunk 31 left poisoned -- computed by T-MFMA, never gathered)
// ---------------------------------------------------------------------------
__global__ __launch_bounds__(256) void relcast_k(
    const float* __restrict__ rel, short* __restrict__ relimg)
{
    const int base = (blockIdx.x * 256 + threadIdx.x) << 3;
    if (base >= 2047 * 64) return;
    const int r = base >> 6, d0 = base & 63;
    float4 f0 = *(const float4*)&rel[base];
    float4 f1 = *(const float4*)&rel[base + 4];
    bf16x8 p;
    p[0] = f2bf(f0.x); p[1] = f2bf(f0.y); p[2] = f2bf(f0.z); p[3] = f2bf(f0.w);
    p[4] = f2bf(f1.x); p[5] = f2bf(f1.y); p[6] = f2bf(f1.z); p[7] = f2bf(f1.w);
    const size_t dst = ((size_t)(r >> 6) << 12) + ((r & 63) << 6)
                     + ((((d0 >> 3) ^ (r & 7))) << 3);
    *(bf16x8*)&relimg[dst] = p;
}

// ---------------------------------------------------------------------------
// m97-style bf16 GEMM with global_load_lds staging. Tile 128 x (NT*32).
// mode 0: fp32 out[row*1024+coln] (bias b0)
// mode 1: bf16; t3=0 (q): plain heads [b,h,l,d]; t3=1 (k): swizzled 8KB tile
//         images per (b,h); t3=2 (v): transposed swizzled tile images [d][j].
// ---------------------------------------------------------------------------
template <int NT>
__global__ __launch_bounds__(256, 2) void gemm_glds_k(
    const short* __restrict__ A, const short* __restrict__ Wt,
    const float* __restrict__ b0, const float* __restrict__ b1,
    const float* __restrict__ b2, void* __restrict__ outv,
    int K, int mode)
{
    constexpr int BN = NT * 32;
    __shared__ short As[128 * 32];
    __shared__ short Bs[BN * 32];

    const int t    = threadIdx.x;
    const int lane = t & 63, w = t >> 6;
    const int m0   = blockIdx.y << 7, n0 = blockIdx.x * BN;
    const int fr   = lane & 15, qd = lane >> 4;
    const int wm0  = (w & 1) << 6, wn0 = (w >> 1) * (NT << 4);

    f32x4 acc[4][NT];
#pragma unroll
    for (int i = 0; i < 4; ++i)
#pragma unroll
        for (int j = 0; j < NT; ++j) acc[i][j] = (f32x4){0.f, 0.f, 0.f, 0.f};

    const short* aSrc = A  + (size_t)(m0 + w * 32 + (lane >> 2)) * K + (lane & 3) * 8;
    const short* bSrc = Wt + (size_t)(n0 + w * (BN / 4) + (lane >> 2)) * K + (lane & 3) * 8;
    short* aDst0 = &As[(w * 32) * 32];
    short* aDst1 = &As[(w * 32 + 16) * 32];
    short* bDst0 = &Bs[(w * (BN / 4)) * 32];
    short* bDst1 = &Bs[(w * (BN / 4) + 16) * 32];

    for (int k0 = 0; k0 < K; k0 += 32) {
        __syncthreads();
        glds16(aSrc + k0, aDst0);
        glds16(aSrc + (size_t)16 * K + k0, aDst1);
        glds16(bSrc + k0, bDst0);
        if (NT == 4) glds16(bSrc + (size_t)16 * K + k0, bDst1);
        __syncthreads();

        bf16x8 af[4], bfv[NT];
#pragma unroll
        for (int mt = 0; mt < 4; ++mt)
            af[mt] = *(const bf16x8*)&As[(wm0 + (mt << 4) + fr) * 32 + (qd << 3)];
#pragma unroll
        for (int nt = 0; nt < NT; ++nt)
            bfv[nt] = *(const bf16x8*)&Bs[(wn0 + (nt << 4) + fr) * 32 + (qd << 3)];
#pragma unroll
        for (int mt = 0; mt < 4; ++mt)
#pragma unroll
            for (int nt = 0; nt < NT; ++nt)
                acc[mt][nt] = __builtin_amdgcn_mfma_f32_16x16x32_bf16(
                    af[mt], bfv[nt], acc[mt][nt], 0, 0, 0);
    }

#pragma unroll
    for (int nt = 0; nt < NT; ++nt) {
        const int coln = n0 + wn0 + (nt << 4) + fr;
        float bias;
        if (mode == 0) bias = b0[coln];
        else {
            const int t3 = coln >> 10;
            bias = (t3 == 0 ? b0 : t3 == 1 ? b1 : b2)[coln & 1023];
        }
#pragma unroll
        for (int mt = 0; mt < 4; ++mt)
#pragma unroll
            for (int rg = 0; rg < 4; ++rg) {
                const int row = m0 + wm0 + (mt << 4) + (qd << 2) + rg;
                const float val = acc[mt][nt][rg] + bias;
                if (mode == 0) {
                    ((float*)outv)[(size_t)row * HID_ + coln] = val;
                } else {
                    const int t3 = coln >> 10;
                    const int h  = (coln >> 6) & 15;
                    const int d  = coln & 63;
                    const int bb = row >> 10, l = row & 1023;
                    const size_t bhoff = ((size_t)(bb * H_ + h)) << 16;
                    size_t dst;
                    if (t3 == 0)        // q: plain [b,h,l,d]
                        dst = bhoff + ((size_t)l << 6) + d;
                    else if (t3 == 1)   // k: swizzled tile image
                        dst = (size_t)HEADSZ_ + bhoff + ((size_t)(l >> 6) << 12)
                            + ((l & 63) << 6) + ((((d >> 3) ^ (l & 7))) << 3) + (d & 7);
                    else                // v: transposed swizzled tile image [d][j=l]
                        dst = 2 * (size_t)HEADSZ_ + bhoff + ((size_t)(l >> 6) << 12)
                            + ((size_t)d << 6) + (((((l >> 3) & 7) ^ (d & 7))) << 3) + (l & 7);
                    ((short*)outv)[dst] = f2bf(val);
                }
            }
    }
}

// ---------------------------------------------------------------------------
// MFMA attention. Per block (b,h,64-row Q tile), 4 waves. Q A-frags in regs.
// K/V/rel staged to LDS via glds16 from pre-swizzled 8KB global images
// (6 glds/wave/tile, async, conflict-free b128 frag reads). Rolling T: one
// new 64-row rel chunk per tile into bf16 Ts[2][64][68] (wave-private cols).
// P roundtrip via Ps[64][72] (wave-private rows). LDS 51200 B -> 3 blk/CU.
// ---------------------------------------------------------------------------
__global__ __launch_bounds__(256, 3) void attn_mfma_k(
    const short* __restrict__ q, const short* __restrict__ kimg,
    const short* __restrict__ vimg, const short* __restrict__ relimg,
    short* __restrict__ ctx)
{
    __shared__ __align__(16) short Ks[64 * 64];
    __shared__ __align__(16) short Vt[64 * 64];
    __shared__ __align__(16) short Rl[64 * 64];
    __shared__ __align__(16) short Ts[2 * 64 * 68];
    __shared__ __align__(16) short Ps[64 * 72];

    const int t    = threadIdx.x;
    const int i0   = blockIdx.x << 6;
    const int h    = blockIdx.y;
    const int b    = blockIdx.z;
    const size_t bh = (size_t)(b * H_ + h) << 16;
    const int lane = t & 63, w = t >> 6;
    const int fr   = lane & 15, qd = lane >> 4;
    const int m16  = i0 >> 6;
    const int iiB  = (w << 4) + (qd << 2);
    const int soff = w * 1024 + lane * 8;   // shorts: wave base + lane*16B

    // Q A-frags (once, from plain layout)
    bf16x8 af[2];
#pragma unroll
    for (int hh = 0; hh < 2; ++hh)
        af[hh] = *(const bf16x8*)&q[bh + ((size_t)(i0 + (w << 4) + fr) << 6)
                                    + (((hh << 2) + qd) << 3)];

    // prologue: stage rel chunk m16+16, T into parity m16&1
    glds16(relimg + ((size_t)(m16 + 16) << 12) + soff,       Rl + w * 1024);
    glds16(relimg + ((size_t)(m16 + 16) << 12) + soff + 512, Rl + w * 1024 + 512);
    __syncthreads();
    {
        f32x4 acc_t[4];
#pragma unroll
        for (int i = 0; i < 4; ++i) acc_t[i] = (f32x4){0.f, 0.f, 0.f, 0.f};
#pragma unroll
        for (int hh = 0; hh < 2; ++hh) {
            const int g = (hh << 2) + qd;
#pragma unroll
            for (int rt = 0; rt < 4; ++rt) {
                const int rr = (rt << 4) + fr;
                bf16x8 br = *(const bf16x8*)&Rl[(rr << 6) + ((g ^ (rr & 7)) << 3)];
                acc_t[rt] = __builtin_amdgcn_mfma_f32_16x16x32_bf16(af[hh], br, acc_t[rt], 0, 0, 0);
            }
        }
        const int pu = m16 & 1;
#pragma unroll
        for (int rt = 0; rt < 4; ++rt) {
            bf16x4 p;
            p[0] = f2bf(acc_t[rt][0]); p[1] = f2bf(acc_t[rt][1]);
            p[2] = f2bf(acc_t[rt][2]); p[3] = f2bf(acc_t[rt][3]);
            *(bf16x4*)&Ts[pu * 4352 + ((rt << 4) + fr) * 68 + iiB] = p;
        }
    }

    f32x4 acc_o[4];
#pragma unroll
    for (int i = 0; i < 4; ++i) acc_o[i] = (f32x4){0.f, 0.f, 0.f, 0.f};
    float den[4] = {0.f, 0.f, 0.f, 0.f};

    for (int jt = 0; jt < 16; ++jt) {
        const int mlow = m16 + 15 - jt;
        const int pl   = mlow & 1;

        __syncthreads();   // prev tile frag reads (incl Rl) done
        glds16(kimg + bh + ((size_t)jt << 12) + soff,       Ks + w * 1024);
        glds16(kimg + bh + ((size_t)jt << 12) + soff + 512, Ks + w * 1024 + 512);
        glds16(vimg + bh + ((size_t)jt << 12) + soff,       Vt + w * 1024);
        glds16(vimg + bh + ((size_t)jt << 12) + soff + 512, Vt + w * 1024 + 512);
        glds16(relimg + ((size_t)mlow << 12) + soff,        Rl + w * 1024);
        glds16(relimg + ((size_t)mlow << 12) + soff + 512,  Rl + w * 1024 + 512);
        __syncthreads();   // staged tiles visible

        // S = Q K^T
        f32x4 acc_s[4];
#pragma unroll
        for (int i = 0; i < 4; ++i) acc_s[i] = (f32x4){0.f, 0.f, 0.f, 0.f};
#pragma unroll
        for (int hh = 0; hh < 2; ++hh) {
            const int g = (hh << 2) + qd;
#pragma unroll
            for (int nt = 0; nt < 4; ++nt) {
                const int rb = (nt << 4) + fr;
                bf16x8 bk = *(const bf16x8*)&Ks[(rb << 6) + ((g ^ (rb & 7)) << 3)];
                acc_s[nt] = __builtin_amdgcn_mfma_f32_16x16x32_bf16(af[hh], bk, acc_s[nt], 0, 0, 0);
            }
        }

        // new T chunk (rows 64*mlow .. +63)
        {
            f32x4 acc_t[4];
#pragma unroll
            for (int i = 0; i < 4; ++i) acc_t[i] = (f32x4){0.f, 0.f, 0.f, 0.f};
#pragma unroll
            for (int hh = 0; hh < 2; ++hh) {
                const int g = (hh << 2) + qd;
#pragma unroll
                for (int rt = 0; rt < 4; ++rt) {
                    const int rr = (rt << 4) + fr;
                    bf16x8 br = *(const bf16x8*)&Rl[(rr << 6) + ((g ^ (rr & 7)) << 3)];
                    acc_t[rt] = __builtin_amdgcn_mfma_f32_16x16x32_bf16(af[hh], br, acc_t[rt], 0, 0, 0);
                }
            }
#pragma unroll
            for (int rt = 0; rt < 4; ++rt) {
                bf16x4 p;
                p[0] = f2bf(acc_t[rt][0]); p[1] = f2bf(acc_t[rt][1]);
                p[2] = f2bf(acc_t[rt][2]); p[3] = f2bf(acc_t[rt][3]);
                *(bf16x4*)&Ts[pl * 4352 + ((rt << 4) + fr) * 68 + iiB] = p;
            }
        }
        // Ts/Ps wave-private (cols/rows owned by wave): lgkm ordering suffices

        // exp + diagonal T gather + P -> LDS (A-layout rows, stride 72)
#pragma unroll
        for (int nt = 0; nt < 4; ++nt) {
            const int jj = (nt << 4) + fr;
#pragma unroll
            for (int rg = 0; rg < 4; ++rg) {
                const int ii = iiB + rg;
                const int r7 = ii - jj + 63;                 // [0,126]
                const int par = pl ^ (r7 >> 6);
                const float tv = bf2f(Ts[par * 4352 + (r7 & 63) * 68 + ii]);
                float s = acc_s[nt][rg] * 0.125f;
                s = fminf(fmaxf(s, -100000.f), 100000.f);
                const float e = __expf(s + tv);
                den[rg] += e;
                Ps[ii * 72 + jj] = f2bf(e);
            }
        }

        // O += P V
#pragma unroll
        for (int hh = 0; hh < 2; ++hh) {
            const int g = (hh << 2) + qd;
            bf16x8 ap = *(const bf16x8*)&Ps[((w << 4) + fr) * 72 + (g << 3)];
#pragma unroll
            for (int nt = 0; nt < 4; ++nt) {
                const int rb = (nt << 4) + fr;
                bf16x8 bv = *(const bf16x8*)&Vt[(rb << 6) + ((g ^ (rb & 7)) << 3)];
                acc_o[nt] = __builtin_amdgcn_mfma_f32_16x16x32_bf16(ap, bv, acc_o[nt], 0, 0, 0);
            }
        }
    }

#pragma unroll
    for (int off = 1; off < 16; off <<= 1)
#pragma unroll
        for (int rg = 0; rg < 4; ++rg)
            den[rg] += __shfl_xor(den[rg], off);

#pragma unroll
    for (int rg = 0; rg < 4; ++rg) {
        const float inv = 1.0f / den[rg];
        const int l = i0 + iiB + rg;
#pragma unroll
        for (int nt = 0; nt < 4; ++nt)
            ctx[((size_t)(b * L_ + l) << 10) + (h << 6) + (nt << 4) + fr] =
                f2bf(acc_o[nt][rg] * inv);
    }
}

// ---------------------------------------------------------------------------
extern "C" void kernel_launch(void* const* d_in, const int* in_sizes, int n_in,
                              void* d_out, int out_size, void* d_ws, size_t ws_size,
                              hipStream_t stream)
{
    const float* x   = (const float*)d_in[0];
    const float* Wq  = (const float*)d_in[1];
    const float* bq  = (const float*)d_in[2];
    const float* Wk  = (const float*)d_in[3];
    const float* bk  = (const float*)d_in[4];
    const float* Wv  = (const float*)d_in[5];
    const float* bv  = (const float*)d_in[6];
    const float* Wo  = (const float*)d_in[7];
    const float* bo  = (const float*)d_in[8];
    const float* rel = (const float*)d_in[9];
    float* out = (float*)d_out;

    short* xb   = (short*)d_ws;                         // 4096x1024 bf16
    short* qkv  = xb + (size_t)HEADSZ_;                 // q plain, k image, v image
    short* cw   = qkv + (size_t)3 * HEADSZ_;            // ctx bf16 [B*L, HID]
    short* wt   = cw + (size_t)HEADSZ_;                 // 4 x HID^2 bf16
    short* relimg = wt + (size_t)4 * HID_ * HID_;       // 32 x 4096 shorts

    const dim3 tb(256);

    xcast_k<<<dim3(2048), tb, 0, stream>>>(x, xb);
    wcast4_k<<<dim3(16, 16, 4), tb, 0, stream>>>(Wq, Wk, Wv, Wo, wt);
    relcast_k<<<dim3(64), tb, 0, stream>>>(rel, relimg);

    // fused QKV GEMM: N=3072, tile 128x128
    gemm_glds_k<4><<<dim3(24, 32), tb, 0, stream>>>(
        xb, wt, bq, bk, bv, qkv, HID_, 1);

    attn_mfma_k<<<dim3(16, H_, B_), tb, 0, stream>>>(
        qkv, qkv + HEADSZ_, qkv + 2 * (size_t)HEADSZ_, relimg, cw);

    // output GEMM: N=1024, tile 128x64
    gemm_glds_k<2><<<dim3(16, 32), tb, 0, stream>>>(
        cw, wt + (size_t)3 * HID_ * HID_, bo, bo, bo, out, HID_, 0);
}